// Round 2
// baseline (1679.967 us; speedup 1.0000x reference)
//
#include <hip/hip_runtime.h>
#include <cstddef>
#include <cstdint>

static constexpr int NN   = 50000;   // nodes
static constexpr int NE   = 800000;  // edges (without self loops)
static constexpr int NG   = 256;     // graphs
static constexpr int FIN  = 128;
static constexpr int HID  = 256;
static constexpr int EMB  = 128;
static constexpr int NGRP = 16;
static constexpr int NFAM = 128;
static constexpr int NETOT = NE + NN;  // edges + self loops

// ---------------- degree / CSR build ----------------

__global__ void k_init_deg(int* __restrict__ degi, int n) {
    int i = blockIdx.x * blockDim.x + threadIdx.x;
    if (i < n) degi[i] = 1;  // self loop
}

__global__ void k_count(const int* __restrict__ edst, int* __restrict__ degi, int e) {
    int i = blockIdx.x * blockDim.x + threadIdx.x;
    if (i < e) atomicAdd(degi + edst[i], 1);
}

__global__ void k_dinv(const int* __restrict__ degi, float* __restrict__ dinv, int n) {
    int i = blockIdx.x * blockDim.x + threadIdx.x;
    if (i < n) dinv[i] = rsqrtf((float)degi[i]);
}

// single-block exclusive scan of (degi[i]-1) -> row_ptr; also zeros cursor
__global__ __launch_bounds__(1024) void k_scan(const int* __restrict__ degi,
                                               int* __restrict__ row_ptr,
                                               int* __restrict__ cursor, int n) {
    __shared__ int ps[1024];
    const int t  = threadIdx.x;
    const int CH = (n + 1023) / 1024;
    int lo = t * CH;
    int hi = min(lo + CH, n);
    int s = 0;
    for (int i = lo; i < hi; ++i) s += degi[i] - 1;
    ps[t] = s;
    __syncthreads();
    for (int off = 1; off < 1024; off <<= 1) {
        int v = (t >= off) ? ps[t - off] : 0;
        __syncthreads();
        if (t >= off) ps[t] += v;
        __syncthreads();
    }
    int run = (t == 0) ? 0 : ps[t - 1];
    for (int i = lo; i < hi; ++i) {
        row_ptr[i] = run;
        cursor[i]  = 0;
        run += degi[i] - 1;
    }
    if (t == 1023) row_ptr[n] = ps[1023];
}

__global__ void k_fill(const int* __restrict__ esrc, const int* __restrict__ edst,
                       const int* __restrict__ row_ptr, int* __restrict__ cursor,
                       int* __restrict__ col, int e) {
    int i = blockIdx.x * blockDim.x + threadIdx.x;
    if (i < e) {
        int d = edst[i];
        int p = atomicAdd(cursor + d, 1);
        col[row_ptr[d] + p] = esrc[i];
    }
}

__global__ void k_gstart(const int* __restrict__ batch, int* __restrict__ gstart,
                         int n, int G) {
    int i = blockIdx.x * blockDim.x + threadIdx.x;
    if (i >= n) return;
    int b  = batch[i];
    int pb = (i == 0) ? -1 : batch[i - 1];
    for (int g = pb + 1; g <= b; ++g) gstart[g] = i;
    if (i == n - 1) {
        for (int g = b + 1; g <= G; ++g) gstart[g] = n;
    }
}

__global__ void k_rcnt(const int* __restrict__ gstart, float* __restrict__ rcnt, int G) {
    int g = blockIdx.x * blockDim.x + threadIdx.x;
    if (g < G) {
        int c = gstart[g + 1] - gstart[g];
        rcnt[g] = 1.0f / (float)max(c, 1);
    }
}

// per-(edge|selfloop): packed src|graph and weight dinv_s*dinv_d*rcnt[g(d)]
__global__ void k_edgeprep(const int* __restrict__ esrc, const int* __restrict__ edst,
                           const int* __restrict__ batch, const float* __restrict__ dinv,
                           const float* __restrict__ rcnt,
                           int* __restrict__ sgE, float* __restrict__ wE,
                           int ne, int ntot) {
    int i = blockIdx.x * blockDim.x + threadIdx.x;
    if (i >= ntot) return;
    int s, d;
    if (i < ne) { s = esrc[i]; d = edst[i]; }
    else        { s = i - ne;  d = s; }
    int g = batch[d];
    sgE[i] = s | (g << 16);             // s < 65536, g < 256
    wE[i]  = dinv[s] * dinv[d] * rcnt[g];
}

// ---------------- chunked gather: xa = S x  (F=128, 8 chunks of 16 floats) --------
// chunk = blockIdx & 7 -> pins each chunk's working set (3.2 MB) to one XCD's L2.

__global__ __launch_bounds__(256) void k_agg_chunk(
        const float* __restrict__ x, const int* __restrict__ row_ptr,
        const int* __restrict__ col, const float* __restrict__ dinv,
        float* __restrict__ xa, int n) {
    const int chunk = blockIdx.x & 7;
    const int nb    = blockIdx.x >> 3;
    const int c0    = chunk * 16;
    const int f     = threadIdx.x & 15;
    const int slot  = threadIdx.x >> 4;  // 0..15
#pragma unroll
    for (int outer = 0; outer < 4; ++outer) {
        int node = nb * 64 + outer * 16 + slot;
        if (node >= n) continue;
        float di  = dinv[node];
        float acc = di * x[(size_t)node * FIN + c0 + f];
        int beg = row_ptr[node], end = row_ptr[node + 1];
        for (int j = beg; j < end; ++j) {
            int s = __builtin_nontemporal_load(col + j);
            acc += dinv[s] * x[(size_t)s * FIN + c0 + f];
        }
        xa[(size_t)node * FIN + c0 + f] = di * acc;
    }
}

// ---------------- fp32 tiled GEMM: C = act(A @ W + bias) ----------------

template <bool RELU>
__global__ __launch_bounds__(256) void k_gemm_bias(
        const float* __restrict__ A, const float* __restrict__ W,
        const float* __restrict__ bias, float* __restrict__ C,
        int M, int N, int K) {
    __shared__ float As[64][68];
    __shared__ float Ws[64][68];
    const int t  = threadIdx.x;
    const int tx = t & 15;
    const int ty = t >> 4;
    const int m0 = blockIdx.x * 64;
    const int n0 = blockIdx.y * 64;

    float acc[4][4] = {};

    for (int k0 = 0; k0 < K; k0 += 64) {
#pragma unroll
        for (int l = 0; l < 4; ++l) {
            int lin = t + l * 256;
            int r   = lin >> 4;
            int c4  = (lin & 15) << 2;
            float4 av = make_float4(0.f, 0.f, 0.f, 0.f);
            int gr = m0 + r;
            if (gr < M) av = *(const float4*)(A + (size_t)gr * K + k0 + c4);
            *(float4*)&As[r][c4] = av;
            float4 wv = *(const float4*)(W + (size_t)(k0 + r) * N + n0 + c4);
            *(float4*)&Ws[r][c4] = wv;
        }
        __syncthreads();
#pragma unroll 8
        for (int kk = 0; kk < 64; ++kk) {
            float a0 = As[ty * 4 + 0][kk];
            float a1 = As[ty * 4 + 1][kk];
            float a2 = As[ty * 4 + 2][kk];
            float a3 = As[ty * 4 + 3][kk];
            float4 b = *(const float4*)&Ws[kk][tx * 4];
            acc[0][0] += a0 * b.x; acc[0][1] += a0 * b.y; acc[0][2] += a0 * b.z; acc[0][3] += a0 * b.w;
            acc[1][0] += a1 * b.x; acc[1][1] += a1 * b.y; acc[1][2] += a1 * b.z; acc[1][3] += a1 * b.w;
            acc[2][0] += a2 * b.x; acc[2][1] += a2 * b.y; acc[2][2] += a2 * b.z; acc[2][3] += a2 * b.w;
            acc[3][0] += a3 * b.x; acc[3][1] += a3 * b.y; acc[3][2] += a3 * b.z; acc[3][3] += a3 * b.w;
        }
        __syncthreads();
    }

    float4 bv = *(const float4*)(bias + n0 + tx * 4);
#pragma unroll
    for (int i = 0; i < 4; ++i) {
        int gr = m0 + ty * 4 + i;
        if (gr < M) {
            float4 o;
            o.x = acc[i][0] + bv.x;
            o.y = acc[i][1] + bv.y;
            o.z = acc[i][2] + bv.z;
            o.w = acc[i][3] + bv.w;
            if (RELU) {
                o.x = fmaxf(o.x, 0.f); o.y = fmaxf(o.y, 0.f);
                o.z = fmaxf(o.z, 0.f); o.w = fmaxf(o.w, 0.f);
            }
            *(float4*)(C + (size_t)gr * N + n0 + tx * 4) = o;
        }
    }
}

// ---------------- pooled scatter: pooled[g] += w_e * h1[src_e]  (chunked) --------
// chunk = cbase + (blockIdx & 7): 16 floats of HID=256; LDS per-graph accumulator.

static constexpr int EPB = 2048;  // edges per block

__global__ __launch_bounds__(256) void k_zero(float* __restrict__ p, int n) {
    int i = blockIdx.x * blockDim.x + threadIdx.x;
    if (i < n) p[i] = 0.f;
}

__global__ __launch_bounds__(256) void k_pool_scatter(
        const float* __restrict__ h1, const int* __restrict__ sgE,
        const float* __restrict__ wE, float* __restrict__ pooled,
        int netot, int cbase) {
    __shared__ float lacc[NG * 17];  // stride 17: bank-spread for random-g atomics
    const int chunk = cbase + (blockIdx.x & 7);
    const int eb    = blockIdx.x >> 3;
    const int c0    = chunk * 16;
    for (int i = threadIdx.x; i < NG * 17; i += 256) lacc[i] = 0.f;
    __syncthreads();

    const int es = threadIdx.x >> 2;        // 0..63 edge slot
    const int fq = (threadIdx.x & 3) * 4;   // 0,4,8,12
    const int e0 = eb * EPB;
#pragma unroll 4
    for (int it = 0; it < EPB / 64; ++it) {
        int e = e0 + it * 64 + es;
        if (e < netot) {
            int   sg = __builtin_nontemporal_load(sgE + e);
            float w  = __builtin_nontemporal_load(wE + e);
            int s = sg & 0xFFFF;
            int g = sg >> 16;
            float4 v = *(const float4*)(h1 + (size_t)s * HID + c0 + fq);
            float* dst = &lacc[g * 17 + fq];
            atomicAdd(dst + 0, w * v.x);
            atomicAdd(dst + 1, w * v.y);
            atomicAdd(dst + 2, w * v.z);
            atomicAdd(dst + 3, w * v.w);
        }
    }
    __syncthreads();
    for (int i = threadIdx.x; i < NG * 16; i += 256) {
        int g = i >> 4, f = i & 15;
        float v = lacc[g * 17 + f];
        if (v != 0.f) atomicAdd(&pooled[(size_t)g * HID + c0 + f], v);
    }
}

// ---------------- emb = pooled @ W2 + b2   [256,256]@[256,128] ----------------

__global__ __launch_bounds__(128) void k_embed(const float* __restrict__ pooled,
                                               const float* __restrict__ W2,
                                               const float* __restrict__ b2,
                                               float* __restrict__ emb) {
    __shared__ float p[HID];
    int g = blockIdx.x, c = threadIdx.x;
    for (int i = c; i < HID; i += 128) p[i] = pooled[(size_t)g * HID + i];
    __syncthreads();
    float a = b2[c];
    for (int k = 0; k < HID; ++k) a += p[k] * W2[(size_t)k * EMB + c];
    emb[(size_t)g * EMB + c] = a;
}

// ---------------- heads: group logits, argmax route, family logits ----------------

__global__ __launch_bounds__(128) void k_head(const float* __restrict__ emb,
                                              const float* __restrict__ Wg,
                                              const float* __restrict__ bg,
                                              const float* __restrict__ Wf,
                                              const float* __restrict__ bf,
                                              float* __restrict__ out_gl,
                                              float* __restrict__ out_fl) {
    __shared__ float e[EMB];
    __shared__ float gl[NGRP];
    __shared__ int ps;
    int g = blockIdx.x, c = threadIdx.x;
    e[c] = emb[g * EMB + c];
    __syncthreads();
    if (c < NGRP) {
        float a = bg[c];
        for (int d = 0; d < EMB; ++d) a += e[d] * Wg[d * NGRP + c];
        gl[c] = a;
        out_gl[g * NGRP + c] = a;
    }
    __syncthreads();
    if (c == 0) {
        int bi = 0;
        float bv = gl[0];
        for (int t2 = 1; t2 < NGRP; ++t2)
            if (gl[t2] > bv) { bv = gl[t2]; bi = t2; }
        ps = bi;
    }
    __syncthreads();
    int p = ps;
    float a = bf[p * NFAM + c];
    for (int d = 0; d < EMB; ++d) a += e[d] * Wf[((size_t)p * EMB + d) * NFAM + c];
    out_fl[g * NFAM + c] = a;
}

// ---------------- launch ----------------

extern "C" void kernel_launch(void* const* d_in, const int* in_sizes, int n_in,
                              void* d_out, int out_size, void* d_ws, size_t ws_size,
                              hipStream_t stream) {
    const float* x   = (const float*)d_in[0];
    const int*   ei  = (const int*)d_in[1];
    const int*   bat = (const int*)d_in[2];
    const float* W1  = (const float*)d_in[3];
    const float* b1  = (const float*)d_in[4];
    const float* W2  = (const float*)d_in[5];
    const float* b2  = (const float*)d_in[6];
    const float* Wg  = (const float*)d_in[7];
    const float* bg  = (const float*)d_in[8];
    const float* Wf  = (const float*)d_in[9];
    const float* bf  = (const float*)d_in[10];

    float* out     = (float*)d_out;
    float* out_emb = out;                        // 256*128
    float* out_gl  = out + (size_t)NG * EMB;     // 256*16
    float* out_fl  = out_gl + (size_t)NG * NGRP; // 256*128

    char* w = (char*)d_ws;
    auto alloc = [&](size_t bytes) {
        char* p = w;
        w += (bytes + 255) & ~(size_t)255;
        return p;
    };
    int*   degi    = (int*)alloc((size_t)NN * 4);
    float* dinv    = (float*)alloc((size_t)NN * 4);
    int*   row_ptr = (int*)alloc((size_t)(NN + 1) * 4);
    int*   cursor  = (int*)alloc((size_t)NN * 4);
    int*   col     = (int*)alloc((size_t)NE * 4);
    int*   gstart  = (int*)alloc((size_t)(NG + 1) * 4);
    float* rcnt    = (float*)alloc((size_t)NG * 4);
    int*   sgE     = (int*)alloc((size_t)NETOT * 4);
    float* wE      = (float*)alloc((size_t)NETOT * 4);
    float* xa      = (float*)alloc((size_t)NN * FIN * 4);
    float* h1      = (float*)alloc((size_t)NN * HID * 4);
    float* pooled  = (float*)alloc((size_t)NG * HID * 4);

    const int* esrc = ei;
    const int* edst = ei + NE;

    // graph structure
    k_init_deg<<<(NN + 255) / 256, 256, 0, stream>>>(degi, NN);
    k_count<<<(NE + 255) / 256, 256, 0, stream>>>(edst, degi, NE);
    k_dinv<<<(NN + 255) / 256, 256, 0, stream>>>(degi, dinv, NN);
    k_scan<<<1, 1024, 0, stream>>>(degi, row_ptr, cursor, NN);
    k_fill<<<(NE + 255) / 256, 256, 0, stream>>>(esrc, edst, row_ptr, cursor, col, NE);
    k_gstart<<<(NN + 255) / 256, 256, 0, stream>>>(bat, gstart, NN, NG);
    k_rcnt<<<1, 256, 0, stream>>>(gstart, rcnt, NG);
    k_edgeprep<<<(NETOT + 255) / 256, 256, 0, stream>>>(esrc, edst, bat, dinv, rcnt,
                                                        sgE, wE, NE, NETOT);

    // layer 1: xa = S x  (chunked gather), then h1 = relu(xa @ W1 + b1)
    {
        int nodeBlocks = (NN + 63) / 64;
        k_agg_chunk<<<nodeBlocks * 8, 256, 0, stream>>>(x, row_ptr, col, dinv, xa, NN);
        dim3 grid((NN + 63) / 64, HID / 64);
        k_gemm_bias<true><<<grid, 256, 0, stream>>>(xa, W1, b1, h1, NN, HID, FIN);
    }

    // layer 2 + pool fused: pooled[g] = sum_e w_e * h1[src_e]; emb = pooled@W2 + b2
    {
        k_zero<<<(NG * HID + 255) / 256, 256, 0, stream>>>(pooled, NG * HID);
        int edgeBlocks = (NETOT + EPB - 1) / EPB;
        k_pool_scatter<<<edgeBlocks * 8, 256, 0, stream>>>(h1, sgE, wE, pooled, NETOT, 0);
        k_pool_scatter<<<edgeBlocks * 8, 256, 0, stream>>>(h1, sgE, wE, pooled, NETOT, 8);
        k_embed<<<NG, 128, 0, stream>>>(pooled, W2, b2, out_emb);
    }

    k_head<<<NG, 128, 0, stream>>>(out_emb, Wg, bg, Wf, bf, out_gl, out_fl);
}

// Round 3
// 507.766 us; speedup vs baseline: 3.3085x; 3.3085x over previous
//
#include <hip/hip_runtime.h>
#include <cstddef>
#include <cstdint>

static constexpr int NN   = 50000;   // nodes
static constexpr int NE   = 800000;  // edges (without self loops)
static constexpr int NG   = 256;     // graphs
static constexpr int FIN  = 128;
static constexpr int HID  = 256;
static constexpr int EMB  = 128;
static constexpr int NGRP = 16;
static constexpr int NFAM = 128;
static constexpr int NETOT = NE + NN;  // edges + self loops

// ---------------- degree / CSR build (self-loops INCLUDED, graph-contiguous) ----

__global__ void k_init_deg(int* __restrict__ degi, int n) {
    int i = blockIdx.x * blockDim.x + threadIdx.x;
    if (i < n) degi[i] = 1;  // self loop
}

__global__ void k_count(const int* __restrict__ edst, int* __restrict__ degi, int e) {
    int i = blockIdx.x * blockDim.x + threadIdx.x;
    if (i < e) atomicAdd(degi + edst[i], 1);
}

__global__ void k_dinv(const int* __restrict__ degi, float* __restrict__ dinv, int n) {
    int i = blockIdx.x * blockDim.x + threadIdx.x;
    if (i < n) dinv[i] = rsqrtf((float)degi[i]);
}

__global__ void k_gstart(const int* __restrict__ batch, int* __restrict__ gstart,
                         int n, int G) {
    int i = blockIdx.x * blockDim.x + threadIdx.x;
    if (i >= n) return;
    int b  = batch[i];
    int pb = (i == 0) ? -1 : batch[i - 1];
    for (int g = pb + 1; g <= b; ++g) gstart[g] = i;
    if (i == n - 1) {
        for (int g = b + 1; g <= G; ++g) gstart[g] = n;
    }
}

__global__ void k_rcnt(const int* __restrict__ gstart, float* __restrict__ rcnt, int G) {
    int g = blockIdx.x * blockDim.x + threadIdx.x;
    if (g < G) {
        int c = gstart[g + 1] - gstart[g];
        rcnt[g] = 1.0f / (float)max(c, 1);
    }
}

// exclusive scan of degi (incl. self) -> row_ptr; cursor init 1 (slot 0 = self loop)
__global__ __launch_bounds__(1024) void k_scan(const int* __restrict__ degi,
                                               int* __restrict__ row_ptr,
                                               int* __restrict__ cursor, int n) {
    __shared__ int ps[1024];
    const int t  = threadIdx.x;
    const int CH = (n + 1023) / 1024;
    int lo = t * CH;
    int hi = min(lo + CH, n);
    int s = 0;
    for (int i = lo; i < hi; ++i) s += degi[i];
    ps[t] = s;
    __syncthreads();
    for (int off = 1; off < 1024; off <<= 1) {
        int v = (t >= off) ? ps[t - off] : 0;
        __syncthreads();
        if (t >= off) ps[t] += v;
        __syncthreads();
    }
    int run = (t == 0) ? 0 : ps[t - 1];
    for (int i = lo; i < hi; ++i) {
        row_ptr[i] = run;
        cursor[i]  = 1;
        run += degi[i];
    }
    if (t == 1023) row_ptr[n] = ps[1023];
}

// self-loop entries at slot 0 of each row
__global__ void k_self(const int* __restrict__ batch, const float* __restrict__ dinv,
                       const float* __restrict__ rcnt, const int* __restrict__ row_ptr,
                       int* __restrict__ col, float* __restrict__ wC, int n) {
    int i = blockIdx.x * blockDim.x + threadIdx.x;
    if (i < n) {
        int p = row_ptr[i];
        col[p] = i;
        float di = dinv[i];
        wC[p] = di * di * rcnt[batch[i]];
    }
}

__global__ void k_fill(const int* __restrict__ esrc, const int* __restrict__ edst,
                       const int* __restrict__ batch, const float* __restrict__ dinv,
                       const float* __restrict__ rcnt, const int* __restrict__ row_ptr,
                       int* __restrict__ cursor, int* __restrict__ col,
                       float* __restrict__ wC, int e) {
    int i = blockIdx.x * blockDim.x + threadIdx.x;
    if (i < e) {
        int d = edst[i];
        int s = esrc[i];
        int p = atomicAdd(cursor + d, 1);
        int idx = row_ptr[d] + p;
        col[idx] = s;
        wC[idx] = dinv[d] * dinv[s] * rcnt[batch[d]];
    }
}

// ---------------- layer-1 gather: xa[i] = dinv_i * sum_{j in row(i)} dinv[col]*x[col] --

__global__ __launch_bounds__(256) void k_agg(
        const float* __restrict__ x, const int* __restrict__ row_ptr,
        const int* __restrict__ col, const float* __restrict__ dinv,
        float* __restrict__ xa, int n) {
    int node = blockIdx.x * 4 + (threadIdx.x >> 6);
    if (node >= n) return;
    int lane = threadIdx.x & 63;
    float accx = 0.f, accy = 0.f;
    int beg = row_ptr[node], end = row_ptr[node + 1];
    for (int j = beg; j < end; ++j) {
        int s = __builtin_nontemporal_load(col + j);
        float ds = dinv[s];
        float2 v = *(const float2*)(x + (size_t)s * FIN + lane * 2);
        accx += ds * v.x;
        accy += ds * v.y;
    }
    float di = dinv[node];
    *(float2*)(xa + (size_t)node * FIN + lane * 2) = make_float2(di * accx, di * accy);
}

// ---------------- fp32 tiled GEMM: C = act(A @ W + bias) ----------------

template <bool RELU>
__global__ __launch_bounds__(256) void k_gemm_bias(
        const float* __restrict__ A, const float* __restrict__ W,
        const float* __restrict__ bias, float* __restrict__ C,
        int M, int N, int K) {
    __shared__ float As[64][68];
    __shared__ float Ws[64][68];
    const int t  = threadIdx.x;
    const int tx = t & 15;
    const int ty = t >> 4;
    const int m0 = blockIdx.x * 64;
    const int n0 = blockIdx.y * 64;

    float acc[4][4] = {};

    for (int k0 = 0; k0 < K; k0 += 64) {
#pragma unroll
        for (int l = 0; l < 4; ++l) {
            int lin = t + l * 256;
            int r   = lin >> 4;
            int c4  = (lin & 15) << 2;
            float4 av = make_float4(0.f, 0.f, 0.f, 0.f);
            int gr = m0 + r;
            if (gr < M) av = *(const float4*)(A + (size_t)gr * K + k0 + c4);
            *(float4*)&As[r][c4] = av;
            float4 wv = *(const float4*)(W + (size_t)(k0 + r) * N + n0 + c4);
            *(float4*)&Ws[r][c4] = wv;
        }
        __syncthreads();
#pragma unroll 8
        for (int kk = 0; kk < 64; ++kk) {
            float a0 = As[ty * 4 + 0][kk];
            float a1 = As[ty * 4 + 1][kk];
            float a2 = As[ty * 4 + 2][kk];
            float a3 = As[ty * 4 + 3][kk];
            float4 b = *(const float4*)&Ws[kk][tx * 4];
            acc[0][0] += a0 * b.x; acc[0][1] += a0 * b.y; acc[0][2] += a0 * b.z; acc[0][3] += a0 * b.w;
            acc[1][0] += a1 * b.x; acc[1][1] += a1 * b.y; acc[1][2] += a1 * b.z; acc[1][3] += a1 * b.w;
            acc[2][0] += a2 * b.x; acc[2][1] += a2 * b.y; acc[2][2] += a2 * b.z; acc[2][3] += a2 * b.w;
            acc[3][0] += a3 * b.x; acc[3][1] += a3 * b.y; acc[3][2] += a3 * b.z; acc[3][3] += a3 * b.w;
        }
        __syncthreads();
    }

    float4 bv = *(const float4*)(bias + n0 + tx * 4);
#pragma unroll
    for (int i = 0; i < 4; ++i) {
        int gr = m0 + ty * 4 + i;
        if (gr < M) {
            float4 o;
            o.x = acc[i][0] + bv.x;
            o.y = acc[i][1] + bv.y;
            o.z = acc[i][2] + bv.z;
            o.w = acc[i][3] + bv.w;
            if (RELU) {
                o.x = fmaxf(o.x, 0.f); o.y = fmaxf(o.y, 0.f);
                o.z = fmaxf(o.z, 0.f); o.w = fmaxf(o.w, 0.f);
            }
            *(float4*)(C + (size_t)gr * N + n0 + tx * 4) = o;
        }
    }
}

// ---------------- layer2+pool: pooled[g] = sum_{j in graph-g edge range} wC[j]*h1[col[j]]
// edges are dst-sorted and batch is sorted => each graph's edges are contiguous.
// 8 blocks per graph; register accumulate; LDS reduce; 256 global atomics/block.

__global__ __launch_bounds__(256) void k_zero(float* __restrict__ p, int n) {
    int i = blockIdx.x * blockDim.x + threadIdx.x;
    if (i < n) p[i] = 0.f;
}

__global__ __launch_bounds__(256) void k_pool_gather(
        const float* __restrict__ h1, const int* __restrict__ row_ptr,
        const int* __restrict__ gstart, const int* __restrict__ col,
        const float* __restrict__ wC, float* __restrict__ pooled) {
    __shared__ float red[4][HID];
    const int g  = blockIdx.x >> 3;
    const int k  = blockIdx.x & 7;
    const int e0 = row_ptr[gstart[g]];
    const int e1 = row_ptr[gstart[g + 1]];
    const int len = e1 - e0;
    const int per = (len + 7) >> 3;
    const int s0  = e0 + k * per;
    const int s1  = min(s0 + per, e1);
    const int lane = threadIdx.x & 63;
    const int wv   = threadIdx.x >> 6;

    float4 acc = make_float4(0.f, 0.f, 0.f, 0.f);
    for (int j = s0 + wv; j < s1; j += 4) {
        int s   = __builtin_nontemporal_load(col + j);
        float w = __builtin_nontemporal_load(wC + j);
        float4 v = *(const float4*)(h1 + (size_t)s * HID + lane * 4);
        acc.x += w * v.x; acc.y += w * v.y; acc.z += w * v.z; acc.w += w * v.w;
    }
    *(float4*)&red[wv][lane * 4] = acc;
    __syncthreads();
    int t = threadIdx.x;  // 0..255 covers HID floats
    float v = red[0][t] + red[1][t] + red[2][t] + red[3][t];
    if (v != 0.f) atomicAdd(&pooled[g * HID + t], v);
}

// ---------------- emb = pooled @ W2 + b2   [256,256]@[256,128] ----------------

__global__ __launch_bounds__(128) void k_embed(const float* __restrict__ pooled,
                                               const float* __restrict__ W2,
                                               const float* __restrict__ b2,
                                               float* __restrict__ emb) {
    __shared__ float p[HID];
    int g = blockIdx.x, c = threadIdx.x;
    for (int i = c; i < HID; i += 128) p[i] = pooled[(size_t)g * HID + i];
    __syncthreads();
    float a = b2[c];
    for (int k = 0; k < HID; ++k) a += p[k] * W2[(size_t)k * EMB + c];
    emb[(size_t)g * EMB + c] = a;
}

// ---------------- heads ----------------

__global__ __launch_bounds__(128) void k_head(const float* __restrict__ emb,
                                              const float* __restrict__ Wg,
                                              const float* __restrict__ bg,
                                              const float* __restrict__ Wf,
                                              const float* __restrict__ bf,
                                              float* __restrict__ out_gl,
                                              float* __restrict__ out_fl) {
    __shared__ float e[EMB];
    __shared__ float gl[NGRP];
    __shared__ int ps;
    int g = blockIdx.x, c = threadIdx.x;
    e[c] = emb[g * EMB + c];
    __syncthreads();
    if (c < NGRP) {
        float a = bg[c];
        for (int d = 0; d < EMB; ++d) a += e[d] * Wg[d * NGRP + c];
        gl[c] = a;
        out_gl[g * NGRP + c] = a;
    }
    __syncthreads();
    if (c == 0) {
        int bi = 0;
        float bv = gl[0];
        for (int t2 = 1; t2 < NGRP; ++t2)
            if (gl[t2] > bv) { bv = gl[t2]; bi = t2; }
        ps = bi;
    }
    __syncthreads();
    int p = ps;
    float a = bf[p * NFAM + c];
    for (int d = 0; d < EMB; ++d) a += e[d] * Wf[((size_t)p * EMB + d) * NFAM + c];
    out_fl[g * NFAM + c] = a;
}

// ---------------- launch ----------------

extern "C" void kernel_launch(void* const* d_in, const int* in_sizes, int n_in,
                              void* d_out, int out_size, void* d_ws, size_t ws_size,
                              hipStream_t stream) {
    const float* x   = (const float*)d_in[0];
    const int*   ei  = (const int*)d_in[1];
    const int*   bat = (const int*)d_in[2];
    const float* W1  = (const float*)d_in[3];
    const float* b1  = (const float*)d_in[4];
    const float* W2  = (const float*)d_in[5];
    const float* b2  = (const float*)d_in[6];
    const float* Wg  = (const float*)d_in[7];
    const float* bg  = (const float*)d_in[8];
    const float* Wf  = (const float*)d_in[9];
    const float* bf  = (const float*)d_in[10];

    float* out     = (float*)d_out;
    float* out_emb = out;                        // 256*128
    float* out_gl  = out + (size_t)NG * EMB;     // 256*16
    float* out_fl  = out_gl + (size_t)NG * NGRP; // 256*128

    char* w = (char*)d_ws;
    auto alloc = [&](size_t bytes) {
        char* p = w;
        w += (bytes + 255) & ~(size_t)255;
        return p;
    };
    int*   degi    = (int*)alloc((size_t)NN * 4);
    float* dinv    = (float*)alloc((size_t)NN * 4);
    int*   row_ptr = (int*)alloc((size_t)(NN + 1) * 4);
    int*   cursor  = (int*)alloc((size_t)NN * 4);
    int*   col     = (int*)alloc((size_t)NETOT * 4);
    float* wC      = (float*)alloc((size_t)NETOT * 4);
    int*   gstart  = (int*)alloc((size_t)(NG + 1) * 4);
    float* rcnt    = (float*)alloc((size_t)NG * 4);
    float* xa      = (float*)alloc((size_t)NN * FIN * 4);
    float* h1      = (float*)alloc((size_t)NN * HID * 4);
    float* pooled  = (float*)alloc((size_t)NG * HID * 4);

    const int* esrc = ei;
    const int* edst = ei + NE;

    // graph structure (CSR incl. self loops, per-edge pool weights)
    k_init_deg<<<(NN + 255) / 256, 256, 0, stream>>>(degi, NN);
    k_count<<<(NE + 255) / 256, 256, 0, stream>>>(edst, degi, NE);
    k_dinv<<<(NN + 255) / 256, 256, 0, stream>>>(degi, dinv, NN);
    k_gstart<<<(NN + 255) / 256, 256, 0, stream>>>(bat, gstart, NN, NG);
    k_rcnt<<<1, 256, 0, stream>>>(gstart, rcnt, NG);
    k_scan<<<1, 1024, 0, stream>>>(degi, row_ptr, cursor, NN);
    k_self<<<(NN + 255) / 256, 256, 0, stream>>>(bat, dinv, rcnt, row_ptr, col, wC, NN);
    k_fill<<<(NE + 255) / 256, 256, 0, stream>>>(esrc, edst, bat, dinv, rcnt, row_ptr,
                                                 cursor, col, wC, NE);

    // layer 1: xa = S x, then h1 = relu(xa @ W1 + b1)
    k_agg<<<(NN + 3) / 4, 256, 0, stream>>>(x, row_ptr, col, dinv, xa, NN);
    {
        dim3 grid((NN + 63) / 64, HID / 64);
        k_gemm_bias<true><<<grid, 256, 0, stream>>>(xa, W1, b1, h1, NN, HID, FIN);
    }

    // layer 2 + pool: pooled[g] = sum over graph-contiguous edges; emb = pooled@W2+b2
    k_zero<<<(NG * HID + 255) / 256, 256, 0, stream>>>(pooled, NG * HID);
    k_pool_gather<<<NG * 8, 256, 0, stream>>>(h1, row_ptr, gstart, col, wC, pooled);
    k_embed<<<NG, 128, 0, stream>>>(pooled, W2, b2, out_emb);

    k_head<<<NG, 128, 0, stream>>>(out_emb, Wg, bg, Wf, bf, out_gl, out_fl);
}